// Round 14
// baseline (276.084 us; speedup 1.0000x reference)
//
#include <hip/hip_runtime.h>
#include <hip/hip_bf16.h>

// ============ INSTRUMENTATION ROUND 2 ============
// Round-11 kernels; ONLY k_gather grid replicated x12 (idempotent) so its
// dispatch crosses the ~44us fill ceiling and surfaces with full counters.
// True G = gather_dur/12, also G = (total - 59.3)/11.
// Plus one real fix: k_out LDS pad 136->132 (8-way -> 4-way read conflict).
#define REP_GATHER 12

#define DM   1024
#define DH   128
#define DL   64
#define NTOK 8192
#define NEXP 65536
#define HK   32

typedef __attribute__((ext_vector_type(4))) float f32x4;
typedef __attribute__((ext_vector_type(8))) short bf16x8;

__device__ __forceinline__ float gelu_sig(float v) {
    return v * __builtin_amdgcn_rcpf(1.0f + __expf(-1.702f * v));
}

__device__ __forceinline__ unsigned short f2bf(float f) {
    union { float f; unsigned u; } v; v.f = f;
    unsigned r = v.u + 0x7FFFu + ((v.u >> 16) & 1u);   // RNE
    return (unsigned short)(r >> 16);
}

__device__ __forceinline__ bf16x8 pack8(const float4& a, const float4& b) {
    bf16x8 r;
    r[0] = (short)f2bf(a.x); r[1] = (short)f2bf(a.y);
    r[2] = (short)f2bf(a.z); r[3] = (short)f2bf(a.w);
    r[4] = (short)f2bf(b.x); r[5] = (short)f2bf(b.y);
    r[6] = (short)f2bf(b.z); r[7] = (short)f2bf(b.w);
    return r;
}

// ---------------- Kernel P ----------------
__global__ __launch_bounds__(256) void k_prep(const float* __restrict__ Wu,
                                              const float* __restrict__ W1,
                                              const float* __restrict__ lat,
                                              unsigned short* __restrict__ Wut,
                                              unsigned short* __restrict__ W1T,
                                              unsigned short* __restrict__ latb) {
    const int b = blockIdx.x;
    const int t = threadIdx.x;
    if (b < 512) {
        const int i = b * 256 + t;
        const int c = i >> 10, k = i & 1023;
        Wut[i] = f2bf(Wu[k * DH + c]);
    } else if (b < 544) {
        const int j = (b - 512) * 256 + t;
        const int c = j >> 6, k = j & 63;
        W1T[j] = f2bf(W1[k * DH + c]);
    } else {
        const size_t base = ((size_t)(b - 544) * 256 + t) * 8;
        float4 v0 = *(const float4*)&lat[base];
        float4 v1 = *(const float4*)&lat[base + 4];
        *(bf16x8*)&latb[base] = pack8(v0, v1);
    }
}

// ---------------- Kernel A: xproj partials, split-K (round-11 verbatim) ----------------
__global__ __launch_bounds__(256) void k_xproj(const float* __restrict__ x,
                                               const unsigned short* __restrict__ Wut,
                                               float* __restrict__ xpart) {
    __shared__ unsigned short As[32][72];
    __shared__ unsigned short Bs[128][72];
    const int t = threadIdx.x;
    const int w = t >> 6, l = t & 63;
    const int fr = l & 15, fh = l >> 4;
    const int row0 = blockIdx.x * 32;
    const int ks = blockIdx.y;
    const int k0 = ks * (DM / 2);
    const int ar = t >> 3, ac = (t & 7) * 8;
    const int bc = t >> 1, bk = (t & 1) * 32;

    f32x4 acc[2][2] = {};
    float4 a0, a1; bf16x8 b0, b1, b2, b3;

    a0 = *(const float4*)&x[(size_t)(row0 + ar) * DM + k0 + ac];
    a1 = *(const float4*)&x[(size_t)(row0 + ar) * DM + k0 + ac + 4];
    b0 = *(const bf16x8*)&Wut[(size_t)bc * DM + k0 + bk];
    b1 = *(const bf16x8*)&Wut[(size_t)bc * DM + k0 + bk + 8];
    b2 = *(const bf16x8*)&Wut[(size_t)bc * DM + k0 + bk + 16];
    b3 = *(const bf16x8*)&Wut[(size_t)bc * DM + k0 + bk + 24];

    for (int it = 0; it < 8; ++it) {
        if (it) __syncthreads();
        *(bf16x8*)&As[ar][ac]      = pack8(a0, a1);
        *(bf16x8*)&Bs[bc][bk]      = b0;
        *(bf16x8*)&Bs[bc][bk + 8]  = b1;
        *(bf16x8*)&Bs[bc][bk + 16] = b2;
        *(bf16x8*)&Bs[bc][bk + 24] = b3;
        __syncthreads();
        if (it < 7) {
            const int kc = k0 + (it + 1) * 64;
            a0 = *(const float4*)&x[(size_t)(row0 + ar) * DM + kc + ac];
            a1 = *(const float4*)&x[(size_t)(row0 + ar) * DM + kc + ac + 4];
            b0 = *(const bf16x8*)&Wut[(size_t)bc * DM + kc + bk];
            b1 = *(const bf16x8*)&Wut[(size_t)bc * DM + kc + bk + 8];
            b2 = *(const bf16x8*)&Wut[(size_t)bc * DM + kc + bk + 16];
            b3 = *(const bf16x8*)&Wut[(size_t)bc * DM + kc + bk + 24];
        }
        #pragma unroll
        for (int kk = 0; kk < 2; ++kk) {
            bf16x8 bv[2];
            #pragma unroll
            for (int n2 = 0; n2 < 2; ++n2)
                bv[n2] = *(bf16x8*)&Bs[w * 32 + n2 * 16 + fr][kk * 32 + fh * 8];
            #pragma unroll
            for (int m = 0; m < 2; ++m) {
                bf16x8 av = *(bf16x8*)&As[m * 16 + fr][kk * 32 + fh * 8];
                #pragma unroll
                for (int n2 = 0; n2 < 2; ++n2)
                    acc[m][n2] = __builtin_amdgcn_mfma_f32_16x16x32_bf16(
                        av, bv[n2], acc[m][n2], 0, 0, 0);
            }
        }
    }
    float* dst = xpart + (size_t)ks * NTOK * DH;
    #pragma unroll
    for (int m = 0; m < 2; ++m)
        #pragma unroll
        for (int n2 = 0; n2 < 2; ++n2)
            #pragma unroll
            for (int r = 0; r < 4; ++r)
                dst[(size_t)(row0 + m * 16 + fh * 4 + r) * DH + w * 32 + n2 * 16 + fr] =
                    acc[m][n2][r];
}

// ---------------- Kernel C: gather (round-11 verbatim, grid x12 idempotent) ----------------
__global__ __launch_bounds__(256) void k_gather(const float* __restrict__ xpart,
                                                const float* __restrict__ scores,
                                                const int* __restrict__ idx,
                                                const unsigned short* __restrict__ latb,
                                                const unsigned short* __restrict__ W1T,
                                                unsigned short* __restrict__ accout) {
    __shared__ unsigned short As[HK][72];
    __shared__ float xp[DH];
    __shared__ float pw[4][HK];
    __shared__ float acts[HK];
    const int n = blockIdx.x % NTOK;
    const int t = threadIdx.x;
    const int w = t >> 6, l = t & 63;
    const int fr = l & 15, fh = l >> 4;

    {
        const int row = t >> 3, c = (t & 7) * 8;
        const int e = idx[n * HK + row];
        *(bf16x8*)&As[row][c] = *(const bf16x8*)&latb[(size_t)e * DL + c];
    }
    if (t < 128)
        xp[t] = xpart[(size_t)n * DH + t] + xpart[(size_t)NTOK * DH + (size_t)n * DH + t];
    bf16x8 bv[2][2];
    #pragma unroll
    for (int n2 = 0; n2 < 2; ++n2)
        #pragma unroll
        for (int kk = 0; kk < 2; ++kk)
            bv[n2][kk] = *(const bf16x8*)
                &W1T[(size_t)(w * 32 + n2 * 16 + fr) * DL + kk * 32 + fh * 8];
    __syncthreads();

    f32x4 acc[2][2] = {};
    #pragma unroll
    for (int kk = 0; kk < 2; ++kk)
        #pragma unroll
        for (int m = 0; m < 2; ++m) {
            bf16x8 av = *(bf16x8*)&As[m * 16 + fr][kk * 32 + fh * 8];
            #pragma unroll
            for (int n2 = 0; n2 < 2; ++n2)
                acc[m][n2] = __builtin_amdgcn_mfma_f32_16x16x32_bf16(
                    av, bv[n2][kk], acc[m][n2], 0, 0, 0);
        }
    #pragma unroll
    for (int m = 0; m < 2; ++m)
        #pragma unroll
        for (int n2 = 0; n2 < 2; ++n2)
            #pragma unroll
            for (int r = 0; r < 4; ++r)
                acc[m][n2][r] = gelu_sig(acc[m][n2][r]);

    {
        float xpv[2];
        #pragma unroll
        for (int n2 = 0; n2 < 2; ++n2) xpv[n2] = xp[w * 32 + n2 * 16 + fr];
        float p[2][4];
        #pragma unroll
        for (int m = 0; m < 2; ++m)
            #pragma unroll
            for (int r = 0; r < 4; ++r) {
                float v = acc[m][0][r] * xpv[0];
                v = fmaf(acc[m][1][r], xpv[1], v);
                v += __shfl_xor(v, 1, 64);
                v += __shfl_xor(v, 2, 64);
                v += __shfl_xor(v, 4, 64);
                v += __shfl_xor(v, 8, 64);
                p[m][r] = v;
            }
        if (fr == 0) {
            #pragma unroll
            for (int m = 0; m < 2; ++m)
                #pragma unroll
                for (int r = 0; r < 4; ++r)
                    pw[w][m * 16 + fh * 4 + r] = p[m][r];
        }
    }
    __syncthreads();

    if (t < HK) {
        float d = pw[0][t] + pw[1][t] + pw[2][t] + pw[3][t];
        acts[t] = gelu_sig(d) * scores[n * HK + t];
    }
    __syncthreads();

    {
        float am[2][4];
        #pragma unroll
        for (int m = 0; m < 2; ++m)
            #pragma unroll
            for (int r = 0; r < 4; ++r)
                am[m][r] = acts[m * 16 + fh * 4 + r];
        #pragma unroll
        for (int n2 = 0; n2 < 2; ++n2) {
            float a = 0.0f;
            #pragma unroll
            for (int m = 0; m < 2; ++m)
                #pragma unroll
                for (int r = 0; r < 4; ++r)
                    a = fmaf(am[m][r], acc[m][n2][r], a);
            a += __shfl_xor(a, 16, 64);
            a += __shfl_xor(a, 32, 64);
            if (fh == 0)
                accout[(size_t)n * DH + w * 32 + n2 * 16 + fr] = f2bf(a);
        }
    }
}

// ---------------- Kernel D: out (pad 136 -> 132: 8-way -> 4-way read conflict) ----------------
__global__ __launch_bounds__(256) void k_out(const unsigned short* __restrict__ acc,
                                             const float* __restrict__ Wv,
                                             float* __restrict__ out) {
    __shared__ unsigned short As[64][132];   // dword stride 66: banks (2fr+4fh)%32
    const int t = threadIdx.x;
    const int w = t >> 6, l = t & 63;
    const int fr = l & 15, fh = l >> 4;
    const int row0 = blockIdx.x * 64;
    const int c0 = blockIdx.y * 128;
    const int ar = t >> 2, ac = (t & 3) * 32;

    {
        const unsigned short* src = &acc[(size_t)(row0 + ar) * DH + ac];
        *(bf16x8*)&As[ar][ac]      = *(const bf16x8*)&src[0];
        *(bf16x8*)&As[ar][ac + 8]  = *(const bf16x8*)&src[8];
        *(bf16x8*)&As[ar][ac + 16] = *(const bf16x8*)&src[16];
        *(bf16x8*)&As[ar][ac + 24] = *(const bf16x8*)&src[24];
    }
    bf16x8 bv[2][4];
    #pragma unroll
    for (int n = 0; n < 2; ++n)
        #pragma unroll
        for (int kk = 0; kk < 4; ++kk)
            #pragma unroll
            for (int b = 0; b < 8; ++b)
                bv[n][kk][b] = (short)f2bf(
                    Wv[(size_t)(kk * 32 + fh * 8 + b) * DM + c0 + w * 32 + n * 16 + fr]);
    __syncthreads();

    f32x4 o[4][2] = {};
    #pragma unroll
    for (int kk = 0; kk < 4; ++kk)
        #pragma unroll
        for (int m = 0; m < 4; ++m) {
            bf16x8 av = *(bf16x8*)&As[m * 16 + fr][kk * 32 + fh * 8];
            #pragma unroll
            for (int n = 0; n < 2; ++n)
                o[m][n] = __builtin_amdgcn_mfma_f32_16x16x32_bf16(
                    av, bv[n][kk], o[m][n], 0, 0, 0);
        }
    #pragma unroll
    for (int m = 0; m < 4; ++m)
        #pragma unroll
        for (int n = 0; n < 2; ++n)
            #pragma unroll
            for (int r = 0; r < 4; ++r)
                out[(size_t)(row0 + m * 16 + fh * 4 + r) * DM + c0 + w * 32 + n * 16 + fr] =
                    o[m][n][r] * 0.25f;
}

extern "C" void kernel_launch(void* const* d_in, const int* in_sizes, int n_in,
                              void* d_out, int out_size, void* d_ws, size_t ws_size,
                              hipStream_t stream) {
    const float* x      = (const float*)d_in[0];
    const float* scores = (const float*)d_in[1];
    const int*   idx    = (const int*)d_in[2];
    const float* lat    = (const float*)d_in[3];
    const float* W1     = (const float*)d_in[4];
    const float* Wu     = (const float*)d_in[5];
    const float* Wv     = (const float*)d_in[6];
    float* out = (float*)d_out;

    float* xpart = (float*)d_ws;
    unsigned short* accbuf = (unsigned short*)(xpart + (size_t)2 * NTOK * DH);
    unsigned short* Wut  = accbuf + (size_t)NTOK * DH;
    unsigned short* W1T  = Wut + (size_t)DH * DM;
    unsigned short* latb = W1T + (size_t)DH * DL;

    k_prep<<<544 + (NEXP * DL / 8) / 256, 256, 0, stream>>>(Wu, W1, lat, Wut, W1T, latb);
    k_xproj<<<dim3(NTOK / 32, 2), 256, 0, stream>>>(x, Wut, xpart);
    k_gather<<<NTOK * REP_GATHER, 256, 0, stream>>>(xpart, scores, idx, latb, W1T, accbuf);
    k_out<<<dim3(NTOK / 64, DM / 128), 256, 0, stream>>>(accbuf, Wv, out);
}

// Round 15
// 58.835 us; speedup vs baseline: 4.6925x; 4.6925x over previous
//
#include <hip/hip_runtime.h>
#include <hip/hip_bf16.h>

#define DM   1024
#define DH   128
#define DL   64
#define NTOK 8192
#define NEXP 65536
#define HK   32

typedef __attribute__((ext_vector_type(4))) float f32x4;
typedef __attribute__((ext_vector_type(8))) short bf16x8;

#if __has_builtin(__builtin_amdgcn_exp2f)
#define EXP2F(x) __builtin_amdgcn_exp2f(x)
#else
#define EXP2F(x) exp2f(x)
#endif

__device__ __forceinline__ float gelu_sig(float v) {
    // v * sigmoid(1.702 v); exp2 with folded constant (1.702*log2e) saves a mul
    return v * __builtin_amdgcn_rcpf(1.0f + EXP2F(-2.4555593f * v));
}

__device__ __forceinline__ unsigned short f2bf(float f) {
    union { float f; unsigned u; } v; v.f = f;
    unsigned r = v.u + 0x7FFFu + ((v.u >> 16) & 1u);   // RNE
    return (unsigned short)(r >> 16);
}

__device__ __forceinline__ bf16x8 pack8(const float4& a, const float4& b) {
    bf16x8 r;
    r[0] = (short)f2bf(a.x); r[1] = (short)f2bf(a.y);
    r[2] = (short)f2bf(a.z); r[3] = (short)f2bf(a.w);
    r[4] = (short)f2bf(b.x); r[5] = (short)f2bf(b.y);
    r[6] = (short)f2bf(b.z); r[7] = (short)f2bf(b.w);
    return r;
}

// ---------------- Kernel P: Wut/W1T transposed bf16 tables + latb bf16 table ----------------
__global__ __launch_bounds__(256) void k_prep(const float* __restrict__ Wu,
                                              const float* __restrict__ W1,
                                              const float* __restrict__ lat,
                                              unsigned short* __restrict__ Wut,
                                              unsigned short* __restrict__ W1T,
                                              unsigned short* __restrict__ latb) {
    const int b = blockIdx.x, t = threadIdx.x;
    if (b < 512) {                       // Wut: 128 x 1024 (transpose)
        const int i = b * 256 + t;
        const int c = i >> 10, k = i & 1023;
        Wut[i] = f2bf(Wu[k * DH + c]);
    } else if (b < 544) {                // W1T: 128 x 64 (transpose)
        const int j = (b - 512) * 256 + t;
        const int c = j >> 6, k = j & 63;
        W1T[j] = f2bf(W1[k * DH + c]);
    } else {                             // latb: straight bf16 convert, 8 elems/thread
        const size_t base = ((size_t)(b - 544) * 256 + t) * 8;
        float4 v0 = *(const float4*)&lat[base];
        float4 v1 = *(const float4*)&lat[base + 4];
        *(bf16x8*)&latb[base] = pack8(v0, v1);
    }
}

// ---------------- Kernel A: xproj partials, split-K ----------------
// Pad 70 (35 dwords, 35%32=3): fragment-read bank = (3*fr+4*fh)%32 ~ 2-way.
__global__ __launch_bounds__(256) void k_xproj(const float* __restrict__ x,
                                               const unsigned short* __restrict__ Wut,
                                               float* __restrict__ xpart) {
    __shared__ unsigned short As[32][70];
    __shared__ unsigned short Bs[128][70];
    const int t = threadIdx.x;
    const int w = t >> 6, l = t & 63;
    const int fr = l & 15, fh = l >> 4;
    const int row0 = blockIdx.x * 32;
    const int ks = blockIdx.y;
    const int k0 = ks * (DM / 2);
    const int ar = t >> 3, ac = (t & 7) * 8;
    const int bc = t >> 1, bk = (t & 1) * 32;

    f32x4 acc[2][2] = {};
    float4 a0, a1; bf16x8 b0, b1, b2, b3;

    a0 = *(const float4*)&x[(size_t)(row0 + ar) * DM + k0 + ac];
    a1 = *(const float4*)&x[(size_t)(row0 + ar) * DM + k0 + ac + 4];
    b0 = *(const bf16x8*)&Wut[(size_t)bc * DM + k0 + bk];
    b1 = *(const bf16x8*)&Wut[(size_t)bc * DM + k0 + bk + 8];
    b2 = *(const bf16x8*)&Wut[(size_t)bc * DM + k0 + bk + 16];
    b3 = *(const bf16x8*)&Wut[(size_t)bc * DM + k0 + bk + 24];

    for (int it = 0; it < 8; ++it) {
        if (it) __syncthreads();
        *(bf16x8*)&As[ar][ac]      = pack8(a0, a1);
        *(bf16x8*)&Bs[bc][bk]      = b0;
        *(bf16x8*)&Bs[bc][bk + 8]  = b1;
        *(bf16x8*)&Bs[bc][bk + 16] = b2;
        *(bf16x8*)&Bs[bc][bk + 24] = b3;
        __syncthreads();
        if (it < 7) {
            const int kc = k0 + (it + 1) * 64;
            a0 = *(const float4*)&x[(size_t)(row0 + ar) * DM + kc + ac];
            a1 = *(const float4*)&x[(size_t)(row0 + ar) * DM + kc + ac + 4];
            b0 = *(const bf16x8*)&Wut[(size_t)bc * DM + kc + bk];
            b1 = *(const bf16x8*)&Wut[(size_t)bc * DM + kc + bk + 8];
            b2 = *(const bf16x8*)&Wut[(size_t)bc * DM + kc + bk + 16];
            b3 = *(const bf16x8*)&Wut[(size_t)bc * DM + kc + bk + 24];
        }
        #pragma unroll
        for (int kk = 0; kk < 2; ++kk) {
            bf16x8 bv[2];
            #pragma unroll
            for (int n2 = 0; n2 < 2; ++n2)
                bv[n2] = *(bf16x8*)&Bs[w * 32 + n2 * 16 + fr][kk * 32 + fh * 8];
            #pragma unroll
            for (int m = 0; m < 2; ++m) {
                bf16x8 av = *(bf16x8*)&As[m * 16 + fr][kk * 32 + fh * 8];
                #pragma unroll
                for (int n2 = 0; n2 < 2; ++n2)
                    acc[m][n2] = __builtin_amdgcn_mfma_f32_16x16x32_bf16(
                        av, bv[n2], acc[m][n2], 0, 0, 0);
            }
        }
    }
    float* dst = xpart + (size_t)ks * NTOK * DH;
    #pragma unroll
    for (int m = 0; m < 2; ++m)
        #pragma unroll
        for (int n2 = 0; n2 < 2; ++n2)
            #pragma unroll
            for (int r = 0; r < 4; ++r)
                dst[(size_t)(row0 + m * 16 + fh * 4 + r) * DH + w * 32 + n2 * 16 + fr] =
                    acc[m][n2][r];
}

// ---------------- Kernel C: gather + MFMA h + fragment-domain dot/accumulate ----------------
__global__ __launch_bounds__(256) void k_gather(const float* __restrict__ xpart,
                                                const float* __restrict__ scores,
                                                const int* __restrict__ idx,
                                                const unsigned short* __restrict__ latb,
                                                const unsigned short* __restrict__ W1T,
                                                unsigned short* __restrict__ accout) {
    __shared__ unsigned short As[HK][70];    // pad 70: 2-way frag reads
    __shared__ float xp[DH];
    __shared__ float pw[4][HK];
    __shared__ float acts[HK];
    const int n = blockIdx.x;
    const int t = threadIdx.x;
    const int w = t >> 6, l = t & 63;
    const int fr = l & 15, fh = l >> 4;

    {
        const int row = t >> 3, c = (t & 7) * 8;
        const int e = idx[n * HK + row];
        *(bf16x8*)&As[row][c] = *(const bf16x8*)&latb[(size_t)e * DL + c];
    }
    if (t < 128)
        xp[t] = xpart[(size_t)n * DH + t] + xpart[(size_t)NTOK * DH + (size_t)n * DH + t];
    bf16x8 bv[2][2];
    #pragma unroll
    for (int n2 = 0; n2 < 2; ++n2)
        #pragma unroll
        for (int kk = 0; kk < 2; ++kk)
            bv[n2][kk] = *(const bf16x8*)
                &W1T[(size_t)(w * 32 + n2 * 16 + fr) * DL + kk * 32 + fh * 8];
    __syncthreads();

    f32x4 acc[2][2] = {};
    #pragma unroll
    for (int kk = 0; kk < 2; ++kk)
        #pragma unroll
        for (int m = 0; m < 2; ++m) {
            bf16x8 av = *(bf16x8*)&As[m * 16 + fr][kk * 32 + fh * 8];
            #pragma unroll
            for (int n2 = 0; n2 < 2; ++n2)
                acc[m][n2] = __builtin_amdgcn_mfma_f32_16x16x32_bf16(
                    av, bv[n2][kk], acc[m][n2], 0, 0, 0);
        }
    #pragma unroll
    for (int m = 0; m < 2; ++m)
        #pragma unroll
        for (int n2 = 0; n2 < 2; ++n2)
            #pragma unroll
            for (int r = 0; r < 4; ++r)
                acc[m][n2][r] = gelu_sig(acc[m][n2][r]);

    {
        float xpv[2];
        #pragma unroll
        for (int n2 = 0; n2 < 2; ++n2) xpv[n2] = xp[w * 32 + n2 * 16 + fr];
        float p[2][4];
        #pragma unroll
        for (int m = 0; m < 2; ++m)
            #pragma unroll
            for (int r = 0; r < 4; ++r) {
                float v = acc[m][0][r] * xpv[0];
                v = fmaf(acc[m][1][r], xpv[1], v);
                v += __shfl_xor(v, 1, 64);
                v += __shfl_xor(v, 2, 64);
                v += __shfl_xor(v, 4, 64);
                v += __shfl_xor(v, 8, 64);
                p[m][r] = v;
            }
        if (fr == 0) {
            #pragma unroll
            for (int m = 0; m < 2; ++m)
                #pragma unroll
                for (int r = 0; r < 4; ++r)
                    pw[w][m * 16 + fh * 4 + r] = p[m][r];
        }
    }
    __syncthreads();

    if (t < HK) {
        float d = pw[0][t] + pw[1][t] + pw[2][t] + pw[3][t];
        acts[t] = gelu_sig(d) * scores[n * HK + t];
    }
    __syncthreads();

    {
        float am[2][4];
        #pragma unroll
        for (int m = 0; m < 2; ++m)
            #pragma unroll
            for (int r = 0; r < 4; ++r)
                am[m][r] = acts[m * 16 + fh * 4 + r];
        #pragma unroll
        for (int n2 = 0; n2 < 2; ++n2) {
            float a = 0.0f;
            #pragma unroll
            for (int m = 0; m < 2; ++m)
                #pragma unroll
                for (int r = 0; r < 4; ++r)
                    a = fmaf(am[m][r], acc[m][n2][r], a);
            a += __shfl_xor(a, 16, 64);
            a += __shfl_xor(a, 32, 64);
            if (fh == 0)
                accout[(size_t)n * DH + w * 32 + n2 * 16 + fr] = f2bf(a);
        }
    }
}

// ---------------- Kernel D: out = (acc @ Wv)/4 ----------------
// Pad 134 (67 dwords, 67%32=3): fragment reads ~2-way.
__global__ __launch_bounds__(256) void k_out(const unsigned short* __restrict__ acc,
                                             const float* __restrict__ Wv,
                                             float* __restrict__ out) {
    __shared__ unsigned short As[64][134];
    const int t = threadIdx.x;
    const int w = t >> 6, l = t & 63;
    const int fr = l & 15, fh = l >> 4;
    const int row0 = blockIdx.x * 64;
    const int c0 = blockIdx.y * 128;
    const int ar = t >> 2, ac = (t & 3) * 32;

    {
        const unsigned short* src = &acc[(size_t)(row0 + ar) * DH + ac];
        *(bf16x8*)&As[ar][ac]      = *(const bf16x8*)&src[0];
        *(bf16x8*)&As[ar][ac + 8]  = *(const bf16x8*)&src[8];
        *(bf16x8*)&As[ar][ac + 16] = *(const bf16x8*)&src[16];
        *(bf16x8*)&As[ar][ac + 24] = *(const bf16x8*)&src[24];
    }
    bf16x8 bv[2][4];
    #pragma unroll
    for (int n = 0; n < 2; ++n)
        #pragma unroll
        for (int kk = 0; kk < 4; ++kk)
            #pragma unroll
            for (int b = 0; b < 8; ++b)
                bv[n][kk][b] = (short)f2bf(
                    Wv[(size_t)(kk * 32 + fh * 8 + b) * DM + c0 + w * 32 + n * 16 + fr]);
    __syncthreads();

    f32x4 o[4][2] = {};
    #pragma unroll
    for (int kk = 0; kk < 4; ++kk)
        #pragma unroll
        for (int m = 0; m < 4; ++m) {
            bf16x8 av = *(bf16x8*)&As[m * 16 + fr][kk * 32 + fh * 8];
            #pragma unroll
            for (int n = 0; n < 2; ++n)
                o[m][n] = __builtin_amdgcn_mfma_f32_16x16x32_bf16(
                    av, bv[n][kk], o[m][n], 0, 0, 0);
        }
    #pragma unroll
    for (int m = 0; m < 4; ++m)
        #pragma unroll
        for (int n = 0; n < 2; ++n)
            #pragma unroll
            for (int r = 0; r < 4; ++r)
                out[(size_t)(row0 + m * 16 + fh * 4 + r) * DM + c0 + w * 32 + n * 16 + fr] =
                    o[m][n][r] * 0.25f;
}

extern "C" void kernel_launch(void* const* d_in, const int* in_sizes, int n_in,
                              void* d_out, int out_size, void* d_ws, size_t ws_size,
                              hipStream_t stream) {
    const float* x      = (const float*)d_in[0];
    const float* scores = (const float*)d_in[1];
    const int*   idx    = (const int*)d_in[2];
    const float* lat    = (const float*)d_in[3];
    const float* W1     = (const float*)d_in[4];
    const float* Wu     = (const float*)d_in[5];
    const float* Wv     = (const float*)d_in[6];
    float* out = (float*)d_out;

    float* xpart = (float*)d_ws;                                   // 2 x 4 MB
    unsigned short* accbuf = (unsigned short*)(xpart + (size_t)2 * NTOK * DH);  // 2 MB
    unsigned short* Wut  = accbuf + (size_t)NTOK * DH;             // 256 KB
    unsigned short* W1T  = Wut + (size_t)DH * DM;                  // 16 KB
    unsigned short* latb = W1T + (size_t)DH * DL;                  // 8.4 MB

    k_prep<<<544 + (NEXP * DL / 8) / 256, 256, 0, stream>>>(Wu, W1, lat, Wut, W1T, latb);
    k_xproj<<<dim3(NTOK / 32, 2), 256, 0, stream>>>(x, Wut, xpart);
    k_gather<<<NTOK, 256, 0, stream>>>(xpart, scores, idx, latb, W1T, accbuf);
    k_out<<<dim3(NTOK / 64, DM / 128), 256, 0, stream>>>(accbuf, Wv, out);
}

// Round 16
// 55.843 us; speedup vs baseline: 4.9439x; 1.0536x over previous
//
#include <hip/hip_runtime.h>
#include <hip/hip_bf16.h>

#define DM   1024
#define DH   128
#define DL   64
#define NTOK 8192
#define NEXP 65536
#define HK   32

typedef __attribute__((ext_vector_type(4))) float f32x4;
typedef __attribute__((ext_vector_type(8))) short bf16x8;

#if __has_builtin(__builtin_amdgcn_exp2f)
#define EXP2F(x) __builtin_amdgcn_exp2f(x)
#else
#define EXP2F(x) exp2f(x)
#endif

__device__ __forceinline__ float gelu_sig(float v) {
    return v * __builtin_amdgcn_rcpf(1.0f + EXP2F(-2.4555593f * v));
}

__device__ __forceinline__ unsigned short f2bf(float f) {
    union { float f; unsigned u; } v; v.f = f;
    unsigned r = v.u + 0x7FFFu + ((v.u >> 16) & 1u);   // RNE
    return (unsigned short)(r >> 16);
}

__device__ __forceinline__ bf16x8 pack8(const float4& a, const float4& b) {
    bf16x8 r;
    r[0] = (short)f2bf(a.x); r[1] = (short)f2bf(a.y);
    r[2] = (short)f2bf(a.z); r[3] = (short)f2bf(a.w);
    r[4] = (short)f2bf(b.x); r[5] = (short)f2bf(b.y);
    r[6] = (short)f2bf(b.z); r[7] = (short)f2bf(b.w);
    return r;
}

// butterfly add via ds_swizzle immediate (xor stays within 32-lane group; no VALU setup)
template <int PAT>
__device__ __forceinline__ float swz_add(float v) {
    return v + __int_as_float(__builtin_amdgcn_ds_swizzle(__float_as_int(v), PAT));
}

// ---------------- Kernel P: Wut/W1T/WvT transposed bf16 tables + latb ----------------
__global__ __launch_bounds__(256) void k_prep(const float* __restrict__ Wu,
                                              const float* __restrict__ W1,
                                              const float* __restrict__ Wv,
                                              const float* __restrict__ lat,
                                              unsigned short* __restrict__ Wut,
                                              unsigned short* __restrict__ W1T,
                                              unsigned short* __restrict__ WvT,
                                              unsigned short* __restrict__ latb) {
    const int b = blockIdx.x, t = threadIdx.x;
    if (b < 512) {                       // Wut[c][k] = Wu[k][c]: 128 x 1024
        const int i = b * 256 + t;
        const int c = i >> 10, k = i & 1023;
        Wut[i] = f2bf(Wu[k * DH + c]);
    } else if (b < 544) {                // W1T[c][k] = W1[k][c]: 128 x 64
        const int j = (b - 512) * 256 + t;
        const int c = j >> 6, k = j & 63;
        W1T[j] = f2bf(W1[k * DH + c]);
    } else if (b < 1056) {               // WvT[d][k] = Wv[k][d]: 1024 x 128
        const int j = (b - 544) * 256 + t;
        const int d = j >> 7, k = j & 127;
        WvT[j] = f2bf(Wv[(size_t)k * DM + d]);
    } else {                             // latb: straight bf16 convert
        const size_t base = ((size_t)(b - 1056) * 256 + t) * 8;
        float4 v0 = *(const float4*)&lat[base];
        float4 v1 = *(const float4*)&lat[base + 4];
        *(bf16x8*)&latb[base] = pack8(v0, v1);
    }
}

// ---------------- Kernel A: xproj partials, split-K (round-15 verbatim) ----------------
__global__ __launch_bounds__(256) void k_xproj(const float* __restrict__ x,
                                               const unsigned short* __restrict__ Wut,
                                               float* __restrict__ xpart) {
    __shared__ unsigned short As[32][70];
    __shared__ unsigned short Bs[128][70];
    const int t = threadIdx.x;
    const int w = t >> 6, l = t & 63;
    const int fr = l & 15, fh = l >> 4;
    const int row0 = blockIdx.x * 32;
    const int ks = blockIdx.y;
    const int k0 = ks * (DM / 2);
    const int ar = t >> 3, ac = (t & 7) * 8;
    const int bc = t >> 1, bk = (t & 1) * 32;

    f32x4 acc[2][2] = {};
    float4 a0, a1; bf16x8 b0, b1, b2, b3;

    a0 = *(const float4*)&x[(size_t)(row0 + ar) * DM + k0 + ac];
    a1 = *(const float4*)&x[(size_t)(row0 + ar) * DM + k0 + ac + 4];
    b0 = *(const bf16x8*)&Wut[(size_t)bc * DM + k0 + bk];
    b1 = *(const bf16x8*)&Wut[(size_t)bc * DM + k0 + bk + 8];
    b2 = *(const bf16x8*)&Wut[(size_t)bc * DM + k0 + bk + 16];
    b3 = *(const bf16x8*)&Wut[(size_t)bc * DM + k0 + bk + 24];

    for (int it = 0; it < 8; ++it) {
        if (it) __syncthreads();
        *(bf16x8*)&As[ar][ac]      = pack8(a0, a1);
        *(bf16x8*)&Bs[bc][bk]      = b0;
        *(bf16x8*)&Bs[bc][bk + 8]  = b1;
        *(bf16x8*)&Bs[bc][bk + 16] = b2;
        *(bf16x8*)&Bs[bc][bk + 24] = b3;
        __syncthreads();
        if (it < 7) {
            const int kc = k0 + (it + 1) * 64;
            a0 = *(const float4*)&x[(size_t)(row0 + ar) * DM + kc + ac];
            a1 = *(const float4*)&x[(size_t)(row0 + ar) * DM + kc + ac + 4];
            b0 = *(const bf16x8*)&Wut[(size_t)bc * DM + kc + bk];
            b1 = *(const bf16x8*)&Wut[(size_t)bc * DM + kc + bk + 8];
            b2 = *(const bf16x8*)&Wut[(size_t)bc * DM + kc + bk + 16];
            b3 = *(const bf16x8*)&Wut[(size_t)bc * DM + kc + bk + 24];
        }
        #pragma unroll
        for (int kk = 0; kk < 2; ++kk) {
            bf16x8 bv[2];
            #pragma unroll
            for (int n2 = 0; n2 < 2; ++n2)
                bv[n2] = *(bf16x8*)&Bs[w * 32 + n2 * 16 + fr][kk * 32 + fh * 8];
            #pragma unroll
            for (int m = 0; m < 2; ++m) {
                bf16x8 av = *(bf16x8*)&As[m * 16 + fr][kk * 32 + fh * 8];
                #pragma unroll
                for (int n2 = 0; n2 < 2; ++n2)
                    acc[m][n2] = __builtin_amdgcn_mfma_f32_16x16x32_bf16(
                        av, bv[n2], acc[m][n2], 0, 0, 0);
            }
        }
    }
    float* dst = xpart + (size_t)ks * NTOK * DH;
    #pragma unroll
    for (int m = 0; m < 2; ++m)
        #pragma unroll
        for (int n2 = 0; n2 < 2; ++n2)
            #pragma unroll
            for (int r = 0; r < 4; ++r)
                dst[(size_t)(row0 + m * 16 + fh * 4 + r) * DH + w * 32 + n2 * 16 + fr] =
                    acc[m][n2][r];
}

// ---------------- Kernel C: gather (ds_swizzle butterflies) ----------------
__global__ __launch_bounds__(256) void k_gather(const float* __restrict__ xpart,
                                                const float* __restrict__ scores,
                                                const int* __restrict__ idx,
                                                const unsigned short* __restrict__ latb,
                                                const unsigned short* __restrict__ W1T,
                                                unsigned short* __restrict__ accout) {
    __shared__ unsigned short As[HK][70];
    __shared__ float xp[DH];
    __shared__ float pw[4][HK];
    __shared__ float acts[HK];
    const int n = blockIdx.x;
    const int t = threadIdx.x;
    const int w = t >> 6, l = t & 63;
    const int fr = l & 15, fh = l >> 4;

    {
        const int row = t >> 3, c = (t & 7) * 8;
        const int e = idx[n * HK + row];
        *(bf16x8*)&As[row][c] = *(const bf16x8*)&latb[(size_t)e * DL + c];
    }
    if (t < 128)
        xp[t] = xpart[(size_t)n * DH + t] + xpart[(size_t)NTOK * DH + (size_t)n * DH + t];
    bf16x8 bv[2][2];
    #pragma unroll
    for (int n2 = 0; n2 < 2; ++n2)
        #pragma unroll
        for (int kk = 0; kk < 2; ++kk)
            bv[n2][kk] = *(const bf16x8*)
                &W1T[(size_t)(w * 32 + n2 * 16 + fr) * DL + kk * 32 + fh * 8];
    __syncthreads();

    f32x4 acc[2][2] = {};
    #pragma unroll
    for (int kk = 0; kk < 2; ++kk)
        #pragma unroll
        for (int m = 0; m < 2; ++m) {
            bf16x8 av = *(bf16x8*)&As[m * 16 + fr][kk * 32 + fh * 8];
            #pragma unroll
            for (int n2 = 0; n2 < 2; ++n2)
                acc[m][n2] = __builtin_amdgcn_mfma_f32_16x16x32_bf16(
                    av, bv[n2][kk], acc[m][n2], 0, 0, 0);
        }
    #pragma unroll
    for (int m = 0; m < 2; ++m)
        #pragma unroll
        for (int n2 = 0; n2 < 2; ++n2)
            #pragma unroll
            for (int r = 0; r < 4; ++r)
                acc[m][n2][r] = gelu_sig(acc[m][n2][r]);

    {
        float xpv[2];
        #pragma unroll
        for (int n2 = 0; n2 < 2; ++n2) xpv[n2] = xp[w * 32 + n2 * 16 + fr];
        float p[2][4];
        #pragma unroll
        for (int m = 0; m < 2; ++m)
            #pragma unroll
            for (int r = 0; r < 4; ++r) {
                float v = acc[m][0][r] * xpv[0];
                v = fmaf(acc[m][1][r], xpv[1], v);
                v = swz_add<0x041F>(v);   // xor 1
                v = swz_add<0x081F>(v);   // xor 2
                v = swz_add<0x101F>(v);   // xor 4
                v = swz_add<0x201F>(v);   // xor 8
                p[m][r] = v;
            }
        if (fr == 0) {
            #pragma unroll
            for (int m = 0; m < 2; ++m)
                #pragma unroll
                for (int r = 0; r < 4; ++r)
                    pw[w][m * 16 + fh * 4 + r] = p[m][r];
        }
    }
    __syncthreads();

    if (t < HK) {
        float d = pw[0][t] + pw[1][t] + pw[2][t] + pw[3][t];
        acts[t] = gelu_sig(d) * scores[n * HK + t];
    }
    __syncthreads();

    {
        float am[2][4];
        #pragma unroll
        for (int m = 0; m < 2; ++m)
            #pragma unroll
            for (int r = 0; r < 4; ++r)
                am[m][r] = acts[m * 16 + fh * 4 + r];
        #pragma unroll
        for (int n2 = 0; n2 < 2; ++n2) {
            float a = 0.0f;
            #pragma unroll
            for (int m = 0; m < 2; ++m)
                #pragma unroll
                for (int r = 0; r < 4; ++r)
                    a = fmaf(am[m][r], acc[m][n2][r], a);
            a = swz_add<0x401F>(a);       // xor 16 (within 32-lane group)
            a += __shfl_xor(a, 32, 64);   // cross-half
            if (fh == 0)
                accout[(size_t)n * DH + w * 32 + n2 * 16 + fr] = f2bf(a);
        }
    }
}

// ---------------- Kernel D: out = (acc @ Wv)/4, B from WvT (vector loads) ----------------
__global__ __launch_bounds__(256) void k_out(const unsigned short* __restrict__ acc,
                                             const unsigned short* __restrict__ WvT,
                                             float* __restrict__ out) {
    __shared__ unsigned short As[64][134];
    const int t = threadIdx.x;
    const int w = t >> 6, l = t & 63;
    const int fr = l & 15, fh = l >> 4;
    const int row0 = blockIdx.x * 64;
    const int c0 = blockIdx.y * 128;
    const int ar = t >> 2, ac = (t & 3) * 32;

    {
        const unsigned short* src = &acc[(size_t)(row0 + ar) * DH + ac];
        *(bf16x8*)&As[ar][ac]      = *(const bf16x8*)&src[0];
        *(bf16x8*)&As[ar][ac + 8]  = *(const bf16x8*)&src[8];
        *(bf16x8*)&As[ar][ac + 16] = *(const bf16x8*)&src[16];
        *(bf16x8*)&As[ar][ac + 24] = *(const bf16x8*)&src[24];
    }
    bf16x8 bv[2][4];
    #pragma unroll
    for (int n = 0; n < 2; ++n)
        #pragma unroll
        for (int kk = 0; kk < 4; ++kk)
            bv[n][kk] = *(const bf16x8*)
                &WvT[(size_t)(c0 + w * 32 + n * 16 + fr) * DH + kk * 32 + fh * 8];
    __syncthreads();

    f32x4 o[4][2] = {};
    #pragma unroll
    for (int kk = 0; kk < 4; ++kk)
        #pragma unroll
        for (int m = 0; m < 4; ++m) {
            bf16x8 av = *(bf16x8*)&As[m * 16 + fr][kk * 32 + fh * 8];
            #pragma unroll
            for (int n = 0; n < 2; ++n)
                o[m][n] = __builtin_amdgcn_mfma_f32_16x16x32_bf16(
                    av, bv[n][kk], o[m][n], 0, 0, 0);
        }
    #pragma unroll
    for (int m = 0; m < 4; ++m)
        #pragma unroll
        for (int n = 0; n < 2; ++n)
            #pragma unroll
            for (int r = 0; r < 4; ++r)
                out[(size_t)(row0 + m * 16 + fh * 4 + r) * DM + c0 + w * 32 + n * 16 + fr] =
                    o[m][n][r] * 0.25f;
}

extern "C" void kernel_launch(void* const* d_in, const int* in_sizes, int n_in,
                              void* d_out, int out_size, void* d_ws, size_t ws_size,
                              hipStream_t stream) {
    const float* x      = (const float*)d_in[0];
    const float* scores = (const float*)d_in[1];
    const int*   idx    = (const int*)d_in[2];
    const float* lat    = (const float*)d_in[3];
    const float* W1     = (const float*)d_in[4];
    const float* Wu     = (const float*)d_in[5];
    const float* Wv     = (const float*)d_in[6];
    float* out = (float*)d_out;

    float* xpart = (float*)d_ws;                                   // 2 x 4 MB
    unsigned short* accbuf = (unsigned short*)(xpart + (size_t)2 * NTOK * DH);  // 2 MB
    unsigned short* Wut  = accbuf + (size_t)NTOK * DH;             // 256 KB
    unsigned short* W1T  = Wut + (size_t)DH * DM;                  // 16 KB
    unsigned short* WvT  = W1T + (size_t)DH * DL;                  // 256 KB
    unsigned short* latb = WvT + (size_t)DM * DH;                  // 8.4 MB

    k_prep<<<1056 + (NEXP * DL / 8) / 256, 256, 0, stream>>>(Wu, W1, Wv, lat,
                                                             Wut, W1T, WvT, latb);
    k_xproj<<<dim3(NTOK / 32, 2), 256, 0, stream>>>(x, Wut, xpart);
    k_gather<<<NTOK, 256, 0, stream>>>(xpart, scores, idx, latb, W1T, accbuf);
    k_out<<<dim3(NTOK / 64, DM / 128), 256, 0, stream>>>(accbuf, WvT, out);
}

// Round 18
// 54.768 us; speedup vs baseline: 5.0410x; 1.0196x over previous
//
#include <hip/hip_runtime.h>
#include <hip/hip_bf16.h>

#define DM   1024
#define DH   128
#define DL   64
#define NTOK 8192
#define NEXP 65536
#define HK   32

typedef __attribute__((ext_vector_type(4))) float f32x4;
typedef __attribute__((ext_vector_type(8))) short bf16x8;

#if __has_builtin(__builtin_amdgcn_exp2f)
#define EXP2F(x) __builtin_amdgcn_exp2f(x)
#else
#define EXP2F(x) exp2f(x)
#endif

__device__ __forceinline__ float gelu_sig(float v) {
    return v * __builtin_amdgcn_rcpf(1.0f + EXP2F(-2.4555593f * v));
}

__device__ __forceinline__ unsigned short f2bf(float f) {
    union { float f; unsigned u; } v; v.f = f;
    unsigned r = v.u + 0x7FFFu + ((v.u >> 16) & 1u);   // RNE
    return (unsigned short)(r >> 16);
}

__device__ __forceinline__ bf16x8 pack8(const float4& a, const float4& b) {
    bf16x8 r;
    r[0] = (short)f2bf(a.x); r[1] = (short)f2bf(a.y);
    r[2] = (short)f2bf(a.z); r[3] = (short)f2bf(a.w);
    r[4] = (short)f2bf(b.x); r[5] = (short)f2bf(b.y);
    r[6] = (short)f2bf(b.z); r[7] = (short)f2bf(b.w);
    return r;
}

// butterfly add via ds_swizzle immediate (xor within 32-lane group; no VALU setup)
template <int PAT>
__device__ __forceinline__ float swz_add(float v) {
    return v + __int_as_float(__builtin_amdgcn_ds_swizzle(__float_as_int(v), PAT));
}

// ---------------- Kernel P: Wut/W1T/WvT transposed bf16 tables (no latb) ----------------
__global__ __launch_bounds__(256) void k_prep(const float* __restrict__ Wu,
                                              const float* __restrict__ W1,
                                              const float* __restrict__ Wv,
                                              unsigned short* __restrict__ Wut,
                                              unsigned short* __restrict__ W1T,
                                              unsigned short* __restrict__ WvT) {
    const int b = blockIdx.x, t = threadIdx.x;
    if (b < 512) {                       // Wut[c][k] = Wu[k][c]: 128 x 1024
        const int i = b * 256 + t;
        const int c = i >> 10, k = i & 1023;
        Wut[i] = f2bf(Wu[k * DH + c]);
    } else if (b < 544) {                // W1T[c][k] = W1[k][c]: 128 x 64
        const int j = (b - 512) * 256 + t;
        const int c = j >> 6, k = j & 63;
        W1T[j] = f2bf(W1[k * DH + c]);
    } else {                             // WvT[d][k] = Wv[k][d]: 1024 x 128
        const int j = (b - 544) * 256 + t;
        const int d = j >> 7, k = j & 127;
        WvT[j] = f2bf(Wv[(size_t)k * DM + d]);
    }
}

// ---------------- Kernel A: xproj partials, split-K (round-16 verbatim) ----------------
__global__ __launch_bounds__(256) void k_xproj(const float* __restrict__ x,
                                               const unsigned short* __restrict__ Wut,
                                               float* __restrict__ xpart) {
    __shared__ unsigned short As[32][70];
    __shared__ unsigned short Bs[128][70];
    const int t = threadIdx.x;
    const int w = t >> 6, l = t & 63;
    const int fr = l & 15, fh = l >> 4;
    const int row0 = blockIdx.x * 32;
    const int ks = blockIdx.y;
    const int k0 = ks * (DM / 2);
    const int ar = t >> 3, ac = (t & 7) * 8;
    const int bc = t >> 1, bk = (t & 1) * 32;

    f32x4 acc[2][2] = {};
    float4 a0, a1; bf16x8 b0, b1, b2, b3;

    a0 = *(const float4*)&x[(size_t)(row0 + ar) * DM + k0 + ac];
    a1 = *(const float4*)&x[(size_t)(row0 + ar) * DM + k0 + ac + 4];
    b0 = *(const bf16x8*)&Wut[(size_t)bc * DM + k0 + bk];
    b1 = *(const bf16x8*)&Wut[(size_t)bc * DM + k0 + bk + 8];
    b2 = *(const bf16x8*)&Wut[(size_t)bc * DM + k0 + bk + 16];
    b3 = *(const bf16x8*)&Wut[(size_t)bc * DM + k0 + bk + 24];

    for (int it = 0; it < 8; ++it) {
        if (it) __syncthreads();
        *(bf16x8*)&As[ar][ac]      = pack8(a0, a1);
        *(bf16x8*)&Bs[bc][bk]      = b0;
        *(bf16x8*)&Bs[bc][bk + 8]  = b1;
        *(bf16x8*)&Bs[bc][bk + 16] = b2;
        *(bf16x8*)&Bs[bc][bk + 24] = b3;
        __syncthreads();
        if (it < 7) {
            const int kc = k0 + (it + 1) * 64;
            a0 = *(const float4*)&x[(size_t)(row0 + ar) * DM + kc + ac];
            a1 = *(const float4*)&x[(size_t)(row0 + ar) * DM + kc + ac + 4];
            b0 = *(const bf16x8*)&Wut[(size_t)bc * DM + kc + bk];
            b1 = *(const bf16x8*)&Wut[(size_t)bc * DM + kc + bk + 8];
            b2 = *(const bf16x8*)&Wut[(size_t)bc * DM + kc + bk + 16];
            b3 = *(const bf16x8*)&Wut[(size_t)bc * DM + kc + bk + 24];
        }
        #pragma unroll
        for (int kk = 0; kk < 2; ++kk) {
            bf16x8 bv[2];
            #pragma unroll
            for (int n2 = 0; n2 < 2; ++n2)
                bv[n2] = *(bf16x8*)&Bs[w * 32 + n2 * 16 + fr][kk * 32 + fh * 8];
            #pragma unroll
            for (int m = 0; m < 2; ++m) {
                bf16x8 av = *(bf16x8*)&As[m * 16 + fr][kk * 32 + fh * 8];
                #pragma unroll
                for (int n2 = 0; n2 < 2; ++n2)
                    acc[m][n2] = __builtin_amdgcn_mfma_f32_16x16x32_bf16(
                        av, bv[n2], acc[m][n2], 0, 0, 0);
            }
        }
    }
    float* dst = xpart + (size_t)ks * NTOK * DH;
    #pragma unroll
    for (int m = 0; m < 2; ++m)
        #pragma unroll
        for (int n2 = 0; n2 < 2; ++n2)
            #pragma unroll
            for (int r = 0; r < 4; ++r)
                dst[(size_t)(row0 + m * 16 + fh * 4 + r) * DH + w * 32 + n2 * 16 + fr] =
                    acc[m][n2][r];
}

// ---------------- Kernel C: gather (fp32 lat staging, r7-verified map) ----------------
__global__ __launch_bounds__(256) void k_gather(const float* __restrict__ xpart,
                                                const float* __restrict__ scores,
                                                const int* __restrict__ idx,
                                                const float* __restrict__ lat,
                                                const unsigned short* __restrict__ W1T,
                                                unsigned short* __restrict__ accout) {
    __shared__ unsigned short As[HK][70];
    __shared__ float xp[DH];
    __shared__ float pw[4][HK];
    __shared__ float acts[HK];
    const int n = blockIdx.x;
    const int t = threadIdx.x;
    const int w = t >> 6, l = t & 63;
    const int fr = l & 15, fh = l >> 4;

    {
        const int row = t >> 3, c = (t & 7) * 8;
        const int e = idx[n * HK + row];         // 8-way broadcast
        const float* src = &lat[(size_t)e * DL + c];
        float4 v0 = *(const float4*)&src[0], v1 = *(const float4*)&src[4];
        *(bf16x8*)&As[row][c] = pack8(v0, v1);
    }
    if (t < 128)
        xp[t] = xpart[(size_t)n * DH + t] + xpart[(size_t)NTOK * DH + (size_t)n * DH + t];
    bf16x8 bv[2][2];
    #pragma unroll
    for (int n2 = 0; n2 < 2; ++n2)
        #pragma unroll
        for (int kk = 0; kk < 2; ++kk)
            bv[n2][kk] = *(const bf16x8*)
                &W1T[(size_t)(w * 32 + n2 * 16 + fr) * DL + kk * 32 + fh * 8];
    __syncthreads();

    f32x4 acc[2][2] = {};
    #pragma unroll
    for (int kk = 0; kk < 2; ++kk)
        #pragma unroll
        for (int m = 0; m < 2; ++m) {
            bf16x8 av = *(bf16x8*)&As[m * 16 + fr][kk * 32 + fh * 8];
            #pragma unroll
            for (int n2 = 0; n2 < 2; ++n2)
                acc[m][n2] = __builtin_amdgcn_mfma_f32_16x16x32_bf16(
                    av, bv[n2][kk], acc[m][n2], 0, 0, 0);
        }
    #pragma unroll
    for (int m = 0; m < 2; ++m)
        #pragma unroll
        for (int n2 = 0; n2 < 2; ++n2)
            #pragma unroll
            for (int r = 0; r < 4; ++r)
                acc[m][n2][r] = gelu_sig(acc[m][n2][r]);

    {
        float xpv[2];
        #pragma unroll
        for (int n2 = 0; n2 < 2; ++n2) xpv[n2] = xp[w * 32 + n2 * 16 + fr];
        float p[2][4];
        #pragma unroll
        for (int m = 0; m < 2; ++m)
            #pragma unroll
            for (int r = 0; r < 4; ++r) {
                float v = acc[m][0][r] * xpv[0];
                v = fmaf(acc[m][1][r], xpv[1], v);
                v = swz_add<0x041F>(v);   // xor 1
                v = swz_add<0x081F>(v);   // xor 2
                v = swz_add<0x101F>(v);   // xor 4
                v = swz_add<0x201F>(v);   // xor 8
                p[m][r] = v;
            }
        if (fr == 0) {
            #pragma unroll
            for (int m = 0; m < 2; ++m)
                #pragma unroll
                for (int r = 0; r < 4; ++r)
                    pw[w][m * 16 + fh * 4 + r] = p[m][r];
        }
    }
    __syncthreads();

    if (t < HK) {
        float d = pw[0][t] + pw[1][t] + pw[2][t] + pw[3][t];
        acts[t] = gelu_sig(d) * scores[n * HK + t];
    }
    __syncthreads();

    {
        float am[2][4];
        #pragma unroll
        for (int m = 0; m < 2; ++m)
            #pragma unroll
            for (int r = 0; r < 4; ++r)
                am[m][r] = acts[m * 16 + fh * 4 + r];
        #pragma unroll
        for (int n2 = 0; n2 < 2; ++n2) {
            float a = 0.0f;
            #pragma unroll
            for (int m = 0; m < 2; ++m)
                #pragma unroll
                for (int r = 0; r < 4; ++r)
                    a = fmaf(am[m][r], acc[m][n2][r], a);
            a = swz_add<0x401F>(a);       // xor 16
            a += __shfl_xor(a, 32, 64);   // cross-half
            if (fh == 0)
                accout[(size_t)n * DH + w * 32 + n2 * 16 + fr] = f2bf(a);
        }
    }
}

// ---------------- Kernel D: out = (acc @ Wv)/4, B from WvT (round-16 verbatim) ----------------
__global__ __launch_bounds__(256) void k_out(const unsigned short* __restrict__ acc,
                                             const unsigned short* __restrict__ WvT,
                                             float* __restrict__ out) {
    __shared__ unsigned short As[64][134];
    const int t = threadIdx.x;
    const int w = t >> 6, l = t & 63;
    const int fr = l & 15, fh = l >> 4;
    const int row0 = blockIdx.x * 64;
    const int c0 = blockIdx.y * 128;
    const int ar = t >> 2, ac = (t & 3) * 32;

    {
        const unsigned short* src = &acc[(size_t)(row0 + ar) * DH + ac];
        *(bf16x8*)&As[ar][ac]      = *(const bf16x8*)&src[0];
        *(bf16x8*)&As[ar][ac + 8]  = *(const bf16x8*)&src[8];
        *(bf16x8*)&As[ar][ac + 16] = *(const bf16x8*)&src[16];
        *(bf16x8*)&As[ar][ac + 24] = *(const bf16x8*)&src[24];
    }
    bf16x8 bv[2][4];
    #pragma unroll
    for (int n = 0; n < 2; ++n)
        #pragma unroll
        for (int kk = 0; kk < 4; ++kk)
            bv[n][kk] = *(const bf16x8*)
                &WvT[(size_t)(c0 + w * 32 + n * 16 + fr) * DH + kk * 32 + fh * 8];
    __syncthreads();

    f32x4 o[4][2] = {};
    #pragma unroll
    for (int kk = 0; kk < 4; ++kk)
        #pragma unroll
        for (int m = 0; m < 4; ++m) {
            bf16x8 av = *(bf16x8*)&As[m * 16 + fr][kk * 32 + fh * 8];
            #pragma unroll
            for (int n = 0; n < 2; ++n)
                o[m][n] = __builtin_amdgcn_mfma_f32_16x16x32_bf16(
                    av, bv[n][kk], o[m][n], 0, 0, 0);
        }
    #pragma unroll
    for (int m = 0; m < 4; ++m)
        #pragma unroll
        for (int n = 0; n < 2; ++n)
            #pragma unroll
            for (int r = 0; r < 4; ++r)
                out[(size_t)(row0 + m * 16 + fh * 4 + r) * DM + c0 + w * 32 + n * 16 + fr] =
                    o[m][n][r] * 0.25f;
}

extern "C" void kernel_launch(void* const* d_in, const int* in_sizes, int n_in,
                              void* d_out, int out_size, void* d_ws, size_t ws_size,
                              hipStream_t stream) {
    const float* x      = (const float*)d_in[0];
    const float* scores = (const float*)d_in[1];
    const int*   idx    = (const int*)d_in[2];
    const float* lat    = (const float*)d_in[3];
    const float* W1     = (const float*)d_in[4];
    const float* Wu     = (const float*)d_in[5];
    const float* Wv     = (const float*)d_in[6];
    float* out = (float*)d_out;

    float* xpart = (float*)d_ws;                                   // 2 x 4 MB
    unsigned short* accbuf = (unsigned short*)(xpart + (size_t)2 * NTOK * DH);  // 2 MB
    unsigned short* Wut  = accbuf + (size_t)NTOK * DH;             // 256 KB
    unsigned short* W1T  = Wut + (size_t)DH * DM;                  // 16 KB
    unsigned short* WvT  = W1T + (size_t)DH * DL;                  // 256 KB

    k_prep<<<1056, 256, 0, stream>>>(Wu, W1, Wv, Wut, W1T, WvT);
    k_xproj<<<dim3(NTOK / 32, 2), 256, 0, stream>>>(x, Wut, xpart);
    k_gather<<<NTOK, 256, 0, stream>>>(xpart, scores, idx, lat, W1T, accbuf);
    k_out<<<dim3(NTOK / 64, DM / 128), 256, 0, stream>>>(accbuf, WvT, out);
}